// Round 7
// baseline (75.765 us; speedup 1.0000x reference)
//
#include <hip/hip_runtime.h>

#define B_ 8192
#define T_ 128
#define I_ 28
#define H_ 64
#define O_ 10
#define RING 8
#define SLOTF 512   // floats per LDS slot: 448 data + 64 pad

typedef __attribute__((ext_vector_type(8))) short bf16x8;
typedef __attribute__((ext_vector_type(4))) float f32x4;
typedef __attribute__((ext_vector_type(4))) unsigned int u32x4;

__device__ __forceinline__ unsigned short f2bf(float f) {
    unsigned int u = __builtin_bit_cast(unsigned int, f);
    u += 0x7fffu + ((u >> 16) & 1u);   // RNE
    return (unsigned short)(u >> 16);
}
__device__ __forceinline__ unsigned int cvtpk(float lo, float hi) {
    unsigned int r;
    asm("v_cvt_pk_bf16_f32 %0, %1, %2" : "=v"(r) : "v"(lo), "v"(hi));
    return r;
}
__device__ __forceinline__ bf16x8 mkfrag(unsigned int a, unsigned int b,
                                         unsigned int c, unsigned int d) {
    u32x4 u = {a, b, c, d};
    return __builtin_bit_cast(bf16x8, u);
}
__device__ __forceinline__ float2 mk2(float a, float b) { float2 r; r.x = a; r.y = b; return r; }
__device__ __forceinline__ float2 pk_mul(float2 a, float2 b) {
    float2 d; asm("v_pk_mul_f32 %0, %1, %2" : "=v"(d) : "v"(a), "v"(b)); return d;
}
__device__ __forceinline__ float2 pk_add(float2 a, float2 b) {
    float2 d; asm("v_pk_add_f32 %0, %1, %2" : "=v"(d) : "v"(a), "v"(b)); return d;
}
__device__ __forceinline__ float2 pk_fma(float2 a, float2 b, float2 c) {
    float2 d; asm("v_pk_fma_f32 %0, %1, %2, %3" : "=v"(d) : "v"(a), "v"(b), "v"(c)); return d;
}

// tanh of two values -> packed bf16x2 with ONE transcendental (merged rcp).
// Pade[7/6]: tanh(x) ~= x(135135+17325t+378t^2+t^3)/(135135+62370t+3150t^2+28t^3),
// t=x^2, |x| clamped to 4.4. Max abs error <= ~3e-4 (below bf16 h quantum).
__device__ __forceinline__ unsigned int tanh2_pade(float xa, float xb) {
    xa = __builtin_amdgcn_fmed3f(xa, -4.4f, 4.4f);
    xb = __builtin_amdgcn_fmed3f(xb, -4.4f, 4.4f);
    float2 xc = mk2(xa, xb);
    float2 t  = pk_mul(xc, xc);
    float2 np = pk_add(t, mk2(378.0f, 378.0f));
    np = pk_fma(np, t, mk2(17325.0f, 17325.0f));
    np = pk_fma(np, t, mk2(135135.0f, 135135.0f));
    float2 num = pk_mul(xc, np);
    float2 dp = pk_fma(t, mk2(28.0f, 28.0f), mk2(3150.0f, 3150.0f));
    dp = pk_fma(dp, t, mk2(62370.0f, 62370.0f));
    dp = pk_fma(dp, t, mk2(135135.0f, 135135.0f));
    float R  = __builtin_amdgcn_rcpf(dp.x * dp.y);   // one rcp for both lanes
    float ra = num.x * dp.y;
    float rb = num.y * dp.x;
    float2 r = pk_mul(mk2(ra, rb), mk2(R, R));
    return cvtpk(r.x, r.y);
}

// async global->LDS: no VGPR destination, so no regalloc hazard; counted by vmcnt
__device__ __forceinline__ void gload_lds(const float* g, float* l) {
    __builtin_amdgcn_global_load_lds(
        (const __attribute__((address_space(1))) unsigned int*)g,
        (__attribute__((address_space(3))) unsigned int*)l, 16, 0, 0);
}

#define MFMA(A, B, C) __builtin_amdgcn_mfma_f32_16x16x32_bf16((A), (B), (C), 0, 0, 0)

__launch_bounds__(64, 1)
__global__ void rnn_reg_kernel(const float* __restrict__ x,
                               const float* __restrict__ W_ih,
                               const float* __restrict__ W_hh,
                               const float* __restrict__ b_ih,
                               const float* __restrict__ b_hh,
                               const float* __restrict__ W_out,
                               const float* __restrict__ b_out,
                               float* __restrict__ out) {
    __shared__ __align__(16) float xs[RING][SLOTF];

    const int lane = threadIdx.x & 63;
    const int m = lane & 15;          // batch row within tile (B-operand col)
    const int g = lane >> 4;          // k-group
    const int row = blockIdx.x * 16 + m;
    const int b0 = blockIdx.x * 16;

    // Swapped-operand MFMA: D = mfma(A=W rows, B=h/x with lane=batch row).
    // Tile t computes physical h-cols n_phys(t,i)=8*(i>>2)+4*(t&1)+(i&3)+32*(t>>1)
    // so lane(g,m) reg r of tile t yields exactly the k-slice it must supply as
    // next step's B-fragment. Recurrence never leaves registers. (Verified R3/R5.)
    bf16x8 wih[4], whhA[4], whhB[4];
    f32x4 biasC[4];
#pragma unroll
    for (int t = 0; t < 4; ++t) {
        const int nA = 8 * (m >> 2) + 4 * (t & 1) + (m & 3) + 32 * (t >> 1);
#pragma unroll
        for (int j = 0; j < 8; ++j) {
            const int k = 8 * g + j;
            wih[t][j]  = (k < I_) ? (short)f2bf(W_ih[nA * I_ + k]) : (short)0;
            whhA[t][j] = (short)f2bf(W_hh[nA * H_ + k]);
            whhB[t][j] = (short)f2bf(W_hh[nA * H_ + 32 + k]);
        }
#pragma unroll
        for (int r = 0; r < 4; ++r) {
            const int nb = 8 * g + 4 * (t & 1) + r + 32 * (t >> 1);
            biasC[t][r] = b_ih[nb] + b_hh[nb];
        }
    }

    // ---- x staging: slot = 16 rows x 112B (7 x 16B chunks per row) ----
    const int cA = lane;
    const int cB = (64 + lane <= 111) ? (64 + lane) : 111;
    const float* gA = x + (size_t)(b0 + cA / 7) * (T_ * I_) + (cA % 7) * 4;
    const float* gB = x + (size_t)(b0 + cB / 7) * (T_ * I_) + (cB % 7) * 4;

#define ISSUE(s, tt) do {                                                    \
        const int tc_ = ((tt) < T_) ? (tt) : (T_ - 1);                       \
        gload_lds(gA + (size_t)tc_ * I_, &xs[s][0]);                         \
        gload_lds(gB + (size_t)tc_ * I_, &xs[s][256]);                       \
    } while (0)

    // consumer: lane(g,m) needs x[row=m][k=8g..8g+7] = floats m*28+8g..+7.
    // g==3's hi half is k=28..31 (zero weights): reread lo instead.
    const int xoff = m * 28 + g * 8;
    const int hoff = (g < 3) ? 4 : 0;

    // Drain weight-setup VMEM so vmcnt counts only the staging loads below.
    __builtin_amdgcn_sched_barrier(0);
    asm volatile("s_waitcnt vmcnt(0)" ::: "memory");
    __builtin_amdgcn_sched_barrier(0);

    ISSUE(0, 0); ISSUE(1, 1); ISSUE(2, 2); ISSUE(3, 3);
    ISSUE(4, 4); ISSUE(5, 5); ISSUE(6, 6); ISSUE(7, 7);

    // x[0]: needed now for px(t=0)
    asm volatile("s_waitcnt vmcnt(14)" ::: "memory");
    __builtin_amdgcn_sched_barrier(0);
    f32x4 px0, px1, px2, px3;
    {
        const f32x4 l0 = *reinterpret_cast<const f32x4*>(&xs[0][xoff]);
        const f32x4 h0v = *reinterpret_cast<const f32x4*>(&xs[0][xoff + hoff]);
        bf16x8 xf0 = mkfrag(cvtpk(l0[0], l0[1]), cvtpk(l0[2], l0[3]),
                            cvtpk(h0v[0], h0v[1]), cvtpk(h0v[2], h0v[3]));
        px0 = MFMA(wih[0], xf0, biasC[0]);
        px1 = MFMA(wih[1], xf0, biasC[1]);
        px2 = MFMA(wih[2], xf0, biasC[2]);
        px3 = MFMA(wih[3], xf0, biasC[3]);
    }
    // x[1]: pre-read into the pending registers (consumed at step 0)
    asm volatile("s_waitcnt vmcnt(12)" ::: "memory");
    __builtin_amdgcn_sched_barrier(0);
    f32x4 loP = *reinterpret_cast<const f32x4*>(&xs[1][xoff]);
    f32x4 hiP = *reinterpret_cast<const f32x4*>(&xs[1][xoff + hoff]);

    bf16x8 h0 = mkfrag(0, 0, 0, 0), h1 = mkfrag(0, 0, 0, 0);

    // Step t (u=t%8): a-MFMAs; xf/px from PENDING regs (x[t+1], read last step
    // => no lgkm stall); vmcnt(10) gates slot (t+2); ds_read it into pending;
    // reissue slot u <- x[t+8]; tanh tail (now trans-light) hides ds/DMA latency.
    // vmcnt: issued x[0..t+7], need x[t+2] done -> x[t+3..t+7] = 10 may remain.
#define STEP(u, SR, TB) do {                                                  \
        f32x4 a0 = MFMA(whhA[0], h0, px0);                                    \
        f32x4 a1 = MFMA(whhA[1], h0, px1);                                    \
        f32x4 a2 = MFMA(whhA[2], h0, px2);                                    \
        f32x4 a3 = MFMA(whhA[3], h0, px3);                                    \
        a0 = MFMA(whhB[0], h1, a0);                                           \
        a1 = MFMA(whhB[1], h1, a1);                                           \
        a2 = MFMA(whhB[2], h1, a2);                                           \
        a3 = MFMA(whhB[3], h1, a3);                                           \
        bf16x8 xf = mkfrag(cvtpk(loP[0], loP[1]), cvtpk(loP[2], loP[3]),      \
                           cvtpk(hiP[0], hiP[1]), cvtpk(hiP[2], hiP[3]));     \
        px0 = MFMA(wih[0], xf, biasC[0]);                                     \
        px1 = MFMA(wih[1], xf, biasC[1]);                                     \
        px2 = MFMA(wih[2], xf, biasC[2]);                                     \
        px3 = MFMA(wih[3], xf, biasC[3]);                                     \
        asm volatile("s_waitcnt vmcnt(10)" ::: "memory");                     \
        __builtin_amdgcn_sched_barrier(0);                                    \
        loP = *reinterpret_cast<const f32x4*>(&xs[SR][xoff]);                 \
        hiP = *reinterpret_cast<const f32x4*>(&xs[SR][xoff + hoff]);          \
        ISSUE(u, (TB) + (u) + 8);                                             \
        __builtin_amdgcn_sched_barrier(0);                                    \
        h0 = mkfrag(tanh2_pade(a0[0], a0[1]), tanh2_pade(a0[2], a0[3]),       \
                    tanh2_pade(a1[0], a1[1]), tanh2_pade(a1[2], a1[3]));      \
        h1 = mkfrag(tanh2_pade(a2[0], a2[1]), tanh2_pade(a2[2], a2[3]),       \
                    tanh2_pade(a3[0], a3[1]), tanh2_pade(a3[2], a3[3]));      \
    } while (0)

    for (int tb = 0; tb < T_; tb += 8) {
        STEP(0, 2, tb); STEP(1, 3, tb); STEP(2, 4, tb); STEP(3, 5, tb);
        STEP(4, 6, tb); STEP(5, 7, tb); STEP(6, 0, tb); STEP(7, 1, tb);
    }
#undef STEP
#undef ISSUE

    // ---- epilogue: out[row][o] = h_last . W_out[o] + b_out[o] ----
    // lane(g,m) holds h_last[row][n] for n in {8g..8g+7} u {32+8g..32+8g+7}
    float hf[16];
    {
        u32x4 H0 = __builtin_bit_cast(u32x4, h0);
        u32x4 H1 = __builtin_bit_cast(u32x4, h1);
#pragma unroll
        for (int p = 0; p < 4; ++p) {
            hf[2 * p]     = __builtin_bit_cast(float, H0[p] << 16);
            hf[2 * p + 1] = __builtin_bit_cast(float, H0[p] & 0xffff0000u);
            hf[8 + 2 * p]     = __builtin_bit_cast(float, H1[p] << 16);
            hf[8 + 2 * p + 1] = __builtin_bit_cast(float, H1[p] & 0xffff0000u);
        }
    }
    float pacc[O_];
#pragma unroll
    for (int o = 0; o < O_; ++o) {
        const float* wo = W_out + o * H_;
        float4 wA = *reinterpret_cast<const float4*>(wo + 8 * g);
        float4 wB = *reinterpret_cast<const float4*>(wo + 8 * g + 4);
        float4 wC = *reinterpret_cast<const float4*>(wo + 32 + 8 * g);
        float4 wD = *reinterpret_cast<const float4*>(wo + 32 + 8 * g + 4);
        float s = hf[0] * wA.x + hf[1] * wA.y + hf[2] * wA.z + hf[3] * wA.w
                + hf[4] * wB.x + hf[5] * wB.y + hf[6] * wB.z + hf[7] * wB.w
                + hf[8] * wC.x + hf[9] * wC.y + hf[10] * wC.z + hf[11] * wC.w
                + hf[12] * wD.x + hf[13] * wD.y + hf[14] * wD.z + hf[15] * wD.w;
        s += __shfl_xor(s, 16);
        s += __shfl_xor(s, 32);
        pacc[o] = s;
    }
    if (g == 0) {
#pragma unroll
        for (int o = 0; o < O_; ++o)
            out[(size_t)row * O_ + o] = pacc[o] + b_out[o];
    }
}

extern "C" void kernel_launch(void* const* d_in, const int* in_sizes, int n_in,
                              void* d_out, int out_size, void* d_ws, size_t ws_size,
                              hipStream_t stream) {
    const float* x     = (const float*)d_in[0];
    const float* W_ih  = (const float*)d_in[1];
    const float* W_hh  = (const float*)d_in[2];
    const float* b_ih  = (const float*)d_in[3];
    const float* b_hh  = (const float*)d_in[4];
    const float* W_out = (const float*)d_in[5];
    const float* b_out = (const float*)d_in[6];
    float* out = (float*)d_out;

    dim3 grid(B_ / 16);
    dim3 block(64);
    rnn_reg_kernel<<<grid, block, 0, stream>>>(x, W_ih, W_hh, b_ih, b_hh,
                                               W_out, b_out, out);
}

// Round 8
// 54.158 us; speedup vs baseline: 1.3990x; 1.3990x over previous
//
#include <hip/hip_runtime.h>

#define B_ 8192
#define T_ 128
#define I_ 28
#define H_ 64
#define O_ 10
#define RING 8
#define SLOTF 512   // floats per x-ring slot: 448 data + 64 pad
#define HS 72       // ushort stride per batch-row in h buffer (144 B, 16B-aligned)

typedef __attribute__((ext_vector_type(8))) short bf16x8;
typedef __attribute__((ext_vector_type(4))) float f32x4;
typedef __attribute__((ext_vector_type(4))) unsigned int u32x4;

__device__ __forceinline__ unsigned short f2bf(float f) {
    unsigned int u = __builtin_bit_cast(unsigned int, f);
    u += 0x7fffu + ((u >> 16) & 1u);   // RNE
    return (unsigned short)(u >> 16);
}
__device__ __forceinline__ unsigned int cvtpk(float lo, float hi) {
    unsigned int r;
    asm("v_cvt_pk_bf16_f32 %0, %1, %2" : "=v"(r) : "v"(lo), "v"(hi));
    return r;
}
__device__ __forceinline__ bf16x8 mkfrag(unsigned int a, unsigned int b,
                                         unsigned int c, unsigned int d) {
    u32x4 u = {a, b, c, d};
    return __builtin_bit_cast(bf16x8, u);
}
__device__ __forceinline__ float exp2f_fast(float x) {
#if __has_builtin(__builtin_amdgcn_exp2f)
    return __builtin_amdgcn_exp2f(x);
#else
    return __expf(x * 0.6931471805599453f);
#endif
}
// tanh pair -> packed bf16x2. tanh(x)=1-2/(1+2^(2*log2e*x)); saturates at +-1.
// Plain scalar ops: let the compiler schedule/interleave freely (R7 lesson).
__device__ __forceinline__ unsigned int tanh2_bf(float xa, float xb) {
    float ta = exp2f_fast(xa * 2.885390081777927f);
    float tb = exp2f_fast(xb * 2.885390081777927f);
    float ra = __builtin_amdgcn_rcpf(1.0f + ta);
    float rb = __builtin_amdgcn_rcpf(1.0f + tb);
    return cvtpk(fmaf(-2.0f, ra, 1.0f), fmaf(-2.0f, rb, 1.0f));
}

// async global->LDS: no VGPR destination (no regalloc hazard); counted by vmcnt
__device__ __forceinline__ void gload_lds(const float* g, float* l) {
    __builtin_amdgcn_global_load_lds(
        (const __attribute__((address_space(1))) unsigned int*)g,
        (__attribute__((address_space(3))) unsigned int*)l, 16, 0, 0);
}

#define MFMA(A, B, C) __builtin_amdgcn_mfma_f32_16x16x32_bf16((A), (B), (C), 0, 0, 0)

__launch_bounds__(256, 1)
__global__ void rnn_split_kernel(const float* __restrict__ x,
                                 const float* __restrict__ W_ih,
                                 const float* __restrict__ W_hh,
                                 const float* __restrict__ b_ih,
                                 const float* __restrict__ b_hh,
                                 const float* __restrict__ W_out,
                                 const float* __restrict__ b_out,
                                 float* __restrict__ out) {
    __shared__ __align__(16) float xs[RING][SLOTF];
    __shared__ __align__(16) unsigned short hb[2][16 * HS];

    const int tid = threadIdx.x;
    const int lane = tid & 63;
    const int w = tid >> 6;           // wave id == output tile (h cols, permuted)
    const int m = lane & 15;          // batch row within tile
    const int g = lane >> 4;          // k-group
    const int b0 = blockIdx.x * 16;
    const int row = b0 + m;

    // Swapped-operand MFMA + permuted-W (verified R3/R5-R7), H split 4 ways:
    // wave w computes h-cols n_phys(w,i)=8*(i>>2)+4*(w&1)+(i&3)+32*(w>>1).
    // Lane(g,m) reg r yields n=8g+4(w&1)+r+32(w>>1): 4 CONTIGUOUS cols ->
    // one b64 LDS write; every wave then b128-reads its full-H B-fragments.
    bf16x8 wih, whhA, whhB;
    f32x4 biasC;
    {
        const int nA = 8 * (m >> 2) + 4 * (w & 1) + (m & 3) + 32 * (w >> 1);
#pragma unroll
        for (int j = 0; j < 8; ++j) {
            const int k = 8 * g + j;
            wih[j]  = (k < I_) ? (short)f2bf(W_ih[nA * I_ + k]) : (short)0;
            whhA[j] = (short)f2bf(W_hh[nA * H_ + k]);
            whhB[j] = (short)f2bf(W_hh[nA * H_ + 32 + k]);
        }
#pragma unroll
        for (int r = 0; r < 4; ++r) {
            const int nb = 8 * g + 4 * (w & 1) + r + 32 * (w >> 1);
            biasC[r] = b_ih[nb] + b_hh[nb];
        }
    }
    const int wbase = m * HS + 8 * g + 4 * (w & 1) + 32 * (w >> 1);  // h write (ushorts)
    const int rbase = m * HS + 8 * g;                                 // h frag read

    // ---- x staging: slot = 16 rows x 112B (7 x 16B chunks/row). All 4 waves
    // issue IDENTICAL DMA (same bytes -> benign; per-wave vmcnt stays sound).
    const int cA = lane;
    const int cB = (64 + lane <= 111) ? (64 + lane) : 111;
    const float* gA = x + (size_t)(b0 + cA / 7) * (T_ * I_) + (cA % 7) * 4;
    const float* gB = x + (size_t)(b0 + cB / 7) * (T_ * I_) + (cB % 7) * 4;

#define ISSUE(s, tt) do {                                                    \
        const int tc_ = ((tt) < T_) ? (tt) : (T_ - 1);                       \
        gload_lds(gA + (size_t)tc_ * I_, &xs[s][0]);                         \
        gload_lds(gB + (size_t)tc_ * I_, &xs[s][256]);                       \
    } while (0)

    const int xoff = m * 28 + g * 8;
    const int hoff = (g < 3) ? 4 : 0;   // g==3 hi half = k 28..31 (zero weights)

#define XFRAG(s, dst) do {                                                   \
        const f32x4 lo_ = *reinterpret_cast<const f32x4*>(&xs[s][xoff]);     \
        const f32x4 hi_ = *reinterpret_cast<const f32x4*>(&xs[s][xoff + hoff]); \
        dst = mkfrag(cvtpk(lo_[0], lo_[1]), cvtpk(lo_[2], lo_[3]),           \
                     cvtpk(hi_[0], hi_[1]), cvtpk(hi_[2], hi_[3]));          \
    } while (0)

    // Drain setup VMEM so vmcnt counts only staging DMA from here on.
    __builtin_amdgcn_sched_barrier(0);
    asm volatile("s_waitcnt vmcnt(0)" ::: "memory");
    __builtin_amdgcn_sched_barrier(0);

    ISSUE(0, 0); ISSUE(1, 1); ISSUE(2, 2); ISSUE(3, 3);
    ISSUE(4, 4); ISSUE(5, 5); ISSUE(6, 6); ISSUE(7, 7);

    asm volatile("s_waitcnt vmcnt(14)" ::: "memory");   // x[0] landed
    __builtin_amdgcn_sched_barrier(0);

    f32x4 px;
    {
        bf16x8 xf0; XFRAG(0, xf0);
        px = MFMA(wih, xf0, biasC);
    }
    bf16x8 h0f = mkfrag(0, 0, 0, 0), h1f = mkfrag(0, 0, 0, 0);

    // Step t (u=t%8): 2 recurrent MFMAs -> tanh(4) -> b64 h-write;
    // lgkm-drain + raw s_barrier (global DMA stays in flight!);
    // read new full-H frags; reissue slot u <- x[t+8]; gate vmcnt(14)
    // (= x[t+2..t+8] outstanding, x[t+1] done); build px(t+1).
#define STEP(u, TB) do {                                                      \
        f32x4 aA = MFMA(whhA, h0f, px);                                       \
        aA = MFMA(whhB, h1f, aA);                                             \
        const unsigned int p0 = tanh2_bf(aA[0], aA[1]);                       \
        const unsigned int p1 = tanh2_bf(aA[2], aA[3]);                       \
        uint2 pv; pv.x = p0; pv.y = p1;                                       \
        *reinterpret_cast<uint2*>(&hb[((u) + 1) & 1][wbase]) = pv;            \
        asm volatile("s_waitcnt lgkmcnt(0)\n\ts_barrier" ::: "memory");       \
        h0f = *reinterpret_cast<const bf16x8*>(&hb[((u) + 1) & 1][rbase]);    \
        h1f = *reinterpret_cast<const bf16x8*>(&hb[((u) + 1) & 1][rbase + 32]); \
        ISSUE(u, (TB) + (u) + 8);                                             \
        asm volatile("s_waitcnt vmcnt(14)" ::: "memory");                     \
        __builtin_amdgcn_sched_barrier(0);                                    \
        bf16x8 xf; XFRAG(((u) + 1) & 7, xf);                                  \
        px = MFMA(wih, xf, biasC);                                            \
    } while (0)

    for (int tb = 0; tb < T_; tb += 8) {
        STEP(0, tb); STEP(1, tb); STEP(2, tb); STEP(3, tb);
        STEP(4, tb); STEP(5, tb); STEP(6, tb); STEP(7, tb);
    }
#undef STEP
#undef XFRAG
#undef ISSUE

    // ---- epilogue: out[row][o] = h_last . W_out[o] + b_out[o] ----
    // All waves hold identical h_last frags; wave 0 does the output.
    if (w == 0) {
        float hf[16];
        {
            u32x4 H0 = __builtin_bit_cast(u32x4, h0f);
            u32x4 H1 = __builtin_bit_cast(u32x4, h1f);
#pragma unroll
            for (int p = 0; p < 4; ++p) {
                hf[2 * p]     = __builtin_bit_cast(float, H0[p] << 16);
                hf[2 * p + 1] = __builtin_bit_cast(float, H0[p] & 0xffff0000u);
                hf[8 + 2 * p]     = __builtin_bit_cast(float, H1[p] << 16);
                hf[8 + 2 * p + 1] = __builtin_bit_cast(float, H1[p] & 0xffff0000u);
            }
        }
        float pacc[O_];
#pragma unroll
        for (int o = 0; o < O_; ++o) {
            const float* wo = W_out + o * H_;
            float4 wA = *reinterpret_cast<const float4*>(wo + 8 * g);
            float4 wB = *reinterpret_cast<const float4*>(wo + 8 * g + 4);
            float4 wC = *reinterpret_cast<const float4*>(wo + 32 + 8 * g);
            float4 wD = *reinterpret_cast<const float4*>(wo + 32 + 8 * g + 4);
            float s = hf[0] * wA.x + hf[1] * wA.y + hf[2] * wA.z + hf[3] * wA.w
                    + hf[4] * wB.x + hf[5] * wB.y + hf[6] * wB.z + hf[7] * wB.w
                    + hf[8] * wC.x + hf[9] * wC.y + hf[10] * wC.z + hf[11] * wC.w
                    + hf[12] * wD.x + hf[13] * wD.y + hf[14] * wD.z + hf[15] * wD.w;
            s += __shfl_xor(s, 16);
            s += __shfl_xor(s, 32);
            pacc[o] = s;
        }
        if (g == 0) {
#pragma unroll
            for (int o = 0; o < O_; ++o)
                out[(size_t)row * O_ + o] = pacc[o] + b_out[o];
        }
    }
}

extern "C" void kernel_launch(void* const* d_in, const int* in_sizes, int n_in,
                              void* d_out, int out_size, void* d_ws, size_t ws_size,
                              hipStream_t stream) {
    const float* x     = (const float*)d_in[0];
    const float* W_ih  = (const float*)d_in[1];
    const float* W_hh  = (const float*)d_in[2];
    const float* b_ih  = (const float*)d_in[3];
    const float* b_hh  = (const float*)d_in[4];
    const float* W_out = (const float*)d_in[5];
    const float* b_out = (const float*)d_in[6];
    float* out = (float*)d_out;

    dim3 grid(B_ / 16);
    dim3 block(256);
    rnn_split_kernel<<<grid, block, 0, stream>>>(x, W_ih, W_hh, b_ih, b_hh,
                                                 W_out, b_out, out);
}

// Round 11
// 44.857 us; speedup vs baseline: 1.6890x; 1.2073x over previous
//
#include <hip/hip_runtime.h>

#define B_ 8192
#define T_ 128
#define I_ 28
#define H_ 64
#define O_ 10
#define RING 8
#define SLOTF 512   // floats per x-ring slot: 448 data + 64 pad
#define HS 72       // ushort stride per batch-row in h buffer (144 B, 16B-aligned)

typedef __attribute__((ext_vector_type(8))) short bf16x8;
typedef __attribute__((ext_vector_type(4))) float f32x4;
typedef __attribute__((ext_vector_type(4))) unsigned int u32x4;

__device__ __forceinline__ unsigned short f2bf(float f) {
    unsigned int u = __builtin_bit_cast(unsigned int, f);
    u += 0x7fffu + ((u >> 16) & 1u);   // RNE
    return (unsigned short)(u >> 16);
}
__device__ __forceinline__ unsigned int cvtpk(float lo, float hi) {
    unsigned int r;
    asm("v_cvt_pk_bf16_f32 %0, %1, %2" : "=v"(r) : "v"(lo), "v"(hi));
    return r;
}
__device__ __forceinline__ bf16x8 mkfrag(unsigned int a, unsigned int b,
                                         unsigned int c, unsigned int d) {
    u32x4 u = {a, b, c, d};
    return __builtin_bit_cast(bf16x8, u);
}
__device__ __forceinline__ float exp2f_fast(float x) {
#if __has_builtin(__builtin_amdgcn_exp2f)
    return __builtin_amdgcn_exp2f(x);
#else
    return __expf(x * 0.6931471805599453f);
#endif
}
// tanh pair -> packed bf16x2. tanh(x)=1-2/(1+2^(2*log2e*x)); saturates at +-1.
// Plain scalar ops: compiler schedules/interleaves freely (R7 lesson).
__device__ __forceinline__ unsigned int tanh2_bf(float xa, float xb) {
    float ta = exp2f_fast(xa * 2.885390081777927f);
    float tb = exp2f_fast(xb * 2.885390081777927f);
    float ra = __builtin_amdgcn_rcpf(1.0f + ta);
    float rb = __builtin_amdgcn_rcpf(1.0f + tb);
    return cvtpk(fmaf(-2.0f, ra, 1.0f), fmaf(-2.0f, rb, 1.0f));
}

// async global->LDS: no VGPR destination (no regalloc hazard); counted by vmcnt
__device__ __forceinline__ void gload_lds(const float* g, float* l) {
    __builtin_amdgcn_global_load_lds(
        (const __attribute__((address_space(1))) unsigned int*)g,
        (__attribute__((address_space(3))) unsigned int*)l, 16, 0, 0);
}

#define MFMA(A, B, C) __builtin_amdgcn_mfma_f32_16x16x32_bf16((A), (B), (C), 0, 0, 0)

__launch_bounds__(256, 1)
__global__ void rnn_split_kernel(const float* __restrict__ x,
                                 const float* __restrict__ W_ih,
                                 const float* __restrict__ W_hh,
                                 const float* __restrict__ b_ih,
                                 const float* __restrict__ b_hh,
                                 const float* __restrict__ W_out,
                                 const float* __restrict__ b_out,
                                 float* __restrict__ out) {
    __shared__ __align__(16) float xs[RING][SLOTF];
    __shared__ __align__(16) unsigned short hb[2][16 * HS];

    const int tid = threadIdx.x;
    const int lane = tid & 63;
    const int w = tid >> 6;           // wave id == output tile (h cols, permuted)
    const int m = lane & 15;          // batch row within tile
    const int g = lane >> 4;          // k-group
    const int b0 = blockIdx.x * 16;
    const int row = b0 + m;

    // Swapped-operand MFMA + permuted-W (verified R3/R5-R8), H split 4 ways:
    // wave w computes h-cols n_phys(w,i)=8*(i>>2)+4*(w&1)+(i&3)+32*(w>>1).
    // Lane(g,m) reg r yields n=8g+4(w&1)+r+32(w>>1): 4 CONTIGUOUS cols ->
    // one b64 LDS write; every wave then b128-reads its full-H B-fragments.
    bf16x8 wih, whhA, whhB;
    f32x4 biasC;
    {
        const int nA = 8 * (m >> 2) + 4 * (w & 1) + (m & 3) + 32 * (w >> 1);
#pragma unroll
        for (int j = 0; j < 8; ++j) {
            const int k = 8 * g + j;
            wih[j]  = (k < I_) ? (short)f2bf(W_ih[nA * I_ + k]) : (short)0;
            whhA[j] = (short)f2bf(W_hh[nA * H_ + k]);
            whhB[j] = (short)f2bf(W_hh[nA * H_ + 32 + k]);
        }
#pragma unroll
        for (int r = 0; r < 4; ++r) {
            const int nb = 8 * g + 4 * (w & 1) + r + 32 * (w >> 1);
            biasC[r] = b_ih[nb] + b_hh[nb];
        }
    }
    const int wbase = m * HS + 8 * g + 4 * (w & 1) + 32 * (w >> 1);  // h write (ushorts)
    const int rbase = m * HS + 8 * g;                                 // h frag read

    // ---- x staging: slot = 16 rows x 112B (7 x 16B chunks/row). ONLY wave 0
    // issues DMA; other waves inherit completion via w0's vmcnt + s_barrier.
    const int cA = lane;
    const int cB = (64 + lane <= 111) ? (64 + lane) : 111;
    const float* gA = x + (size_t)(b0 + cA / 7) * (T_ * I_) + (cA % 7) * 4;
    const float* gB = x + (size_t)(b0 + cB / 7) * (T_ * I_) + (cB % 7) * 4;

#define ISSUE(s, tt) do {                                                    \
        const int tc_ = ((tt) < T_) ? (tt) : (T_ - 1);                       \
        gload_lds(gA + (size_t)tc_ * I_, &xs[s][0]);                         \
        gload_lds(gB + (size_t)tc_ * I_, &xs[s][256]);                       \
    } while (0)

    const int xoff = m * 28 + g * 8;
    const int hoff = (g < 3) ? 4 : 0;   // g==3 hi half = k 28..31 (zero weights)

#define XFRAG(s, dst) do {                                                   \
        const f32x4 lo_ = *reinterpret_cast<const f32x4*>(&xs[s][xoff]);     \
        const f32x4 hi_ = *reinterpret_cast<const f32x4*>(&xs[s][xoff + hoff]); \
        dst = mkfrag(cvtpk(lo_[0], lo_[1]), cvtpk(lo_[2], lo_[3]),           \
                     cvtpk(hi_[0], hi_[1]), cvtpk(hi_[2], hi_[3]));          \
    } while (0)

    // Drain setup VMEM so w0's vmcnt counts only staging DMA from here on.
    __builtin_amdgcn_sched_barrier(0);
    asm volatile("s_waitcnt vmcnt(0)" ::: "memory");
    __builtin_amdgcn_sched_barrier(0);

    if (w == 0) {
        ISSUE(0, 0); ISSUE(1, 1); ISSUE(2, 2); ISSUE(3, 3);
        ISSUE(4, 4); ISSUE(5, 5); ISSUE(6, 6); ISSUE(7, 7);
        // slots 0,1,2 landed when <=10 of the 16 remain outstanding
        asm volatile("s_waitcnt vmcnt(10)" ::: "memory");
    }
    asm volatile("s_barrier" ::: "memory");   // publish x slots 0..2

    f32x4 pxA, pxB;   // px pipelined ONE step ahead (computed early, off-chain)
    {
        bf16x8 xf0; XFRAG(0, xf0);
        pxA = MFMA(wih, xf0, biasC);          // px(t=0)
    }
    bf16x8 h0f = mkfrag(0, 0, 0, 0), h1f = mkfrag(0, 0, 0, 0);

    // Body for time t (u=t%8, PXC=px(t) from last step, PXN=px(t+1) out):
    //   XFRAG(t+1)+px-MFMA issue at TOP (off the recurrence chain; consumed
    //   next step), then chain: recA->recB->tanh->write->barrier->h-read.
    //   w0 reissues slot u <- x[t+8] and gates vmcnt(10) so slots t+1..t+3
    //   are landed+published at every barrier.
#define STEP(u, TB, PXC, PXN) do {                                            \
        bf16x8 xf; XFRAG(((u) + 1) & 7, xf);                                  \
        PXN = MFMA(wih, xf, biasC);                                           \
        f32x4 aA = MFMA(whhA, h0f, PXC);                                      \
        aA = MFMA(whhB, h1f, aA);                                             \
        const unsigned int p0 = tanh2_bf(aA[0], aA[1]);                       \
        const unsigned int p1 = tanh2_bf(aA[2], aA[3]);                       \
        uint2 pv; pv.x = p0; pv.y = p1;                                       \
        *reinterpret_cast<uint2*>(&hb[((u) + 1) & 1][wbase]) = pv;            \
        if (w == 0) {                                                         \
            ISSUE((u), (TB) + (u) + 8);                                       \
            asm volatile("s_waitcnt vmcnt(10)" ::: "memory");                 \
        }                                                                     \
        asm volatile("s_waitcnt lgkmcnt(0)\n\ts_barrier" ::: "memory");       \
        h0f = *reinterpret_cast<const bf16x8*>(&hb[((u) + 1) & 1][rbase]);    \
        h1f = *reinterpret_cast<const bf16x8*>(&hb[((u) + 1) & 1][rbase + 32]); \
    } while (0)

    for (int tb = 0; tb < T_; tb += 8) {
        STEP(0, tb, pxA, pxB); STEP(1, tb, pxB, pxA);
        STEP(2, tb, pxA, pxB); STEP(3, tb, pxB, pxA);
        STEP(4, tb, pxA, pxB); STEP(5, tb, pxB, pxA);
        STEP(6, tb, pxA, pxB); STEP(7, tb, pxB, pxA);
    }
#undef STEP
#undef XFRAG
#undef ISSUE

    // ---- epilogue: out[row][o] = h_last . W_out[o] + b_out[o] ----
    // All waves hold identical h_last frags; wave 0 does the output.
    if (w == 0) {
        float hf[16];
        {
            u32x4 H0 = __builtin_bit_cast(u32x4, h0f);
            u32x4 H1 = __builtin_bit_cast(u32x4, h1f);
#pragma unroll
            for (int p = 0; p < 4; ++p) {
                hf[2 * p]     = __builtin_bit_cast(float, H0[p] << 16);
                hf[2 * p + 1] = __builtin_bit_cast(float, H0[p] & 0xffff0000u);
                hf[8 + 2 * p]     = __builtin_bit_cast(float, H1[p] << 16);
                hf[8 + 2 * p + 1] = __builtin_bit_cast(float, H1[p] & 0xffff0000u);
            }
        }
        float pacc[O_];
#pragma unroll
        for (int o = 0; o < O_; ++o) {
            const float* wo = W_out + o * H_;
            float4 wA = *reinterpret_cast<const float4*>(wo + 8 * g);
            float4 wB = *reinterpret_cast<const float4*>(wo + 8 * g + 4);
            float4 wC = *reinterpret_cast<const float4*>(wo + 32 + 8 * g);
            float4 wD = *reinterpret_cast<const float4*>(wo + 32 + 8 * g + 4);
            float s = hf[0] * wA.x + hf[1] * wA.y + hf[2] * wA.z + hf[3] * wA.w
                    + hf[4] * wB.x + hf[5] * wB.y + hf[6] * wB.z + hf[7] * wB.w
                    + hf[8] * wC.x + hf[9] * wC.y + hf[10] * wC.z + hf[11] * wC.w
                    + hf[12] * wD.x + hf[13] * wD.y + hf[14] * wD.z + hf[15] * wD.w;
            s += __shfl_xor(s, 16);
            s += __shfl_xor(s, 32);
            pacc[o] = s;
        }
        if (g == 0) {
#pragma unroll
            for (int o = 0; o < O_; ++o)
                out[(size_t)row * O_ + o] = pacc[o] + b_out[o];
        }
    }
}

extern "C" void kernel_launch(void* const* d_in, const int* in_sizes, int n_in,
                              void* d_out, int out_size, void* d_ws, size_t ws_size,
                              hipStream_t stream) {
    const float* x     = (const float*)d_in[0];
    const float* W_ih  = (const float*)d_in[1];
    const float* W_hh  = (const float*)d_in[2];
    const float* b_ih  = (const float*)d_in[3];
    const float* b_hh  = (const float*)d_in[4];
    const float* W_out = (const float*)d_in[5];
    const float* b_out = (const float*)d_in[6];
    float* out = (float*)d_out;

    dim3 grid(B_ / 16);
    dim3 block(256);
    rnn_split_kernel<<<grid, block, 0, stream>>>(x, W_ih, W_hh, b_ih, b_hh,
                                                 W_out, b_out, out);
}